// Round 9
// baseline (201.754 us; speedup 1.0000x reference)
//
#include <hip/hip_runtime.h>
#include <hip/hip_bf16.h>
#include <stdint.h>

typedef __attribute__((ext_vector_type(8))) short short8;
typedef __attribute__((ext_vector_type(4))) float f32x4;
typedef __attribute__((ext_vector_type(4))) unsigned short ushort4v;

#define MFMA_BF16(a,b,c) __builtin_amdgcn_mfma_f32_16x16x32_bf16((a),(b),(c),0,0,0)

static __device__ __forceinline__ unsigned short f2bf(float f){
  union { float fv; unsigned int u; } c; c.fv = f;
  unsigned int u = c.u;
  return (unsigned short)((u + 0x7fffu + ((u >> 16) & 1u)) >> 16);
}

static __device__ __forceinline__ unsigned int cvtpk(float a, float b){
  unsigned int r;
  asm("v_cvt_pk_bf16_f32 %0, %1, %2" : "=v"(r) : "v"(a), "v"(b));
  return r;
}

static __device__ __forceinline__ void gload_lds16(const void* g, void* l){
  __builtin_amdgcn_global_load_lds(
      (const __attribute__((address_space(1))) void*)g,
      (__attribute__((address_space(3))) void*)l, 16, 0, 0);
}

static __device__ __forceinline__ float wred_sum(float v){
  #pragma unroll
  for (int m = 32; m; m >>= 1) v += __shfl_xor(v, m, 64);
  return v;
}

static __device__ __forceinline__ void unpack8(uint4 u, float* f){
  f[0] = __uint_as_float(u.x << 16); f[1] = __uint_as_float(u.x & 0xFFFF0000u);
  f[2] = __uint_as_float(u.y << 16); f[3] = __uint_as_float(u.y & 0xFFFF0000u);
  f[4] = __uint_as_float(u.z << 16); f[5] = __uint_as_float(u.z & 0xFFFF0000u);
  f[6] = __uint_as_float(u.w << 16); f[7] = __uint_as_float(u.w & 0xFFFF0000u);
}

// ---------------- conversion kernels ----------------
__global__ __launch_bounds__(256) void cvt_x_kernel(const float* __restrict__ x,
                                                    unsigned short* __restrict__ o){
  int i = blockIdx.x * 256 + threadIdx.x;
  float4 f = ((const float4*)x)[i];
  ushort4v r;
  r[0] = f2bf(f.x); r[1] = f2bf(f.y); r[2] = f2bf(f.z); r[3] = f2bf(f.w);
  ((ushort4v*)o)[i] = r;
}

__global__ __launch_bounds__(256) void cvt_w_kernel(const float* __restrict__ Wq,
                                                    const float* __restrict__ Wk,
                                                    const float* __restrict__ Wv,
                                                    const float* __restrict__ Ws,
                                                    unsigned short* __restrict__ B){
  int i = blockIdx.x * 256 + threadIdx.x;
  int which = i >> 18;
  const float* src = (which == 0) ? Wq : (which == 1) ? Wk : (which == 2) ? Wv : Ws;
  float4 f = ((const float4*)src)[i & 262143];
  ushort4v r;
  r[0] = f2bf(f.x); r[1] = f2bf(f.y); r[2] = f2bf(f.z); r[3] = f2bf(f.w);
  ((ushort4v*)B)[i] = r;
}

__global__ void wb_prep_kernel(const float* __restrict__ Wb,
                               float* __restrict__ wba, float* __restrict__ wbb){
  int e = blockIdx.x * 256 + threadIdx.x;
  if (e < 1024){
    wba[e] = Wb[e]        + Wb[2048 + e];
    wbb[e] = Wb[1024 + e] - Wb[2048 + e];
  }
}

// masks -> bit planes via ballot
__global__ __launch_bounds__(256) void mask_prep_kernel(
    const int* __restrict__ m, const int* __restrict__ wm,
    unsigned long long* __restrict__ mb, unsigned long long* __restrict__ wb)
{
  const size_t i = (size_t)blockIdx.x * 256 + threadIdx.x;
  const int a = m[i];
  const int c = wm[i];
  unsigned long long ba = __ballot(a != 0);
  unsigned long long bc = __ballot(c != 0);
  if ((threadIdx.x & 63) == 0){
    mb[i >> 6] = ba;
    wb[i >> 6] = bc;
  }
}

// ---------------- fused projection GEMM ----------------
// 128x128 tile, 4 waves, BK=32, mt-outer XCD swizzle (A-slice L2-resident).
// K-loop LDS tiles use 16B-chunk XOR swizzle (source pre-swizzle + read XOR)
// to kill ds_read_b128 bank imbalance. Epilogue stages C in LDS for 16B stores.
__global__ __launch_bounds__(256, 4) void gemm_proj_kernel(
    const unsigned short* __restrict__ X, const unsigned short* __restrict__ B,
    unsigned short* __restrict__ qb, unsigned short* __restrict__ kb,
    unsigned short* __restrict__ vT, unsigned short* __restrict__ rbb)
{
  __shared__ __align__(16) unsigned short smem[128 * 136];   // As(4096)+Bs(4096) alias C-tile
  unsigned short* As = smem;
  unsigned short* Bs = smem + 4096;
  const int tid = threadIdx.x;
  const int w = tid >> 6, l = tid & 63;
  const int lr = l & 15, lq = l >> 4;
  const int wr = w >> 1, wc = w & 1;
  const int bid = ((blockIdx.x & 7) << 8) | (blockIdx.x >> 3);   // XCD swizzle (2048 = 8*256)
  const int m0 = (bid >> 5) * 128;         // mt-outer: 8 mt/XCD -> A slice 2MB L2-fits
  const int n0 = (bid & 31) * 128;
  const int gsw = (lr >> 1) & 3;           // read-side chunk XOR
  f32x4 acc[4][4] = {};

  for (int k0 = 0; k0 < 1024; k0 += 32){
    #pragma unroll
    for (int i = 0; i < 2; i++){
      const int c = i * 256 + tid;
      const int row = c >> 2;
      const int cgs = (c & 3) ^ ((c >> 3) & 3);   // source pre-swizzle: (col)^( (row>>1)&3 )
      gload_lds16(X + (size_t)(m0 + row) * 1024 + k0 + cgs * 8,
                  As + (i * 256 + w * 64) * 8);
      gload_lds16(B + (size_t)(n0 + row) * 1024 + k0 + cgs * 8,
                  Bs + (i * 256 + w * 64) * 8);
    }
    __syncthreads();
    short8 av[4], bv[4];
    #pragma unroll
    for (int mf = 0; mf < 4; mf++)
      av[mf] = *(const short8*)(As + (wr * 64 + mf * 16 + lr) * 32 + (lq ^ gsw) * 8);
    #pragma unroll
    for (int nf = 0; nf < 4; nf++)
      bv[nf] = *(const short8*)(Bs + (wc * 64 + nf * 16 + lr) * 32 + (lq ^ gsw) * 8);
    #pragma unroll
    for (int mf = 0; mf < 4; mf++)
      #pragma unroll
      for (int nf = 0; nf < 4; nf++)
        acc[mf][nf] = MFMA_BF16(av[mf], bv[nf], acc[mf][nf]);
    __syncthreads();
  }

  const int which = (n0 >> 10);
  const int o0 = n0 & 1023;
  if (which == 2){
    // v: transposed LDS staging [col][row], stride 132, packed b64 writes
    #pragma unroll
    for (int mf = 0; mf < 4; mf++)
      #pragma unroll
      for (int nf = 0; nf < 4; nf++){
        const int r0 = wr * 64 + mf * 16 + lq * 4;
        const int c  = wc * 64 + nf * 16 + lr;
        uint2 pk;
        pk.x = cvtpk(acc[mf][nf][0], acc[mf][nf][1]);
        pk.y = cvtpk(acc[mf][nf][2], acc[mf][nf][3]);
        *(uint2*)(smem + c * 132 + r0) = pk;
      }
    __syncthreads();
    const int s0 = m0 >> 4;
    #pragma unroll
    for (int p = 0; p < 8; p++){
      const int cid = p * 256 + tid;
      const int c = cid >> 4, bb = cid & 15;
      short8 st;
      #pragma unroll
      for (int j = 0; j < 8; j++) st[j] = (short)smem[c * 132 + j * 16 + bb];
      const int o = o0 + c;
      const int bh = bb * 16 + (o >> 6), d = o & 63;
      *(short8*)(vT + ((size_t)bh * 64 + d) * 512 + s0) = st;
    }
  } else {
    // q/k/r: row-major LDS staging [row][136], b128 reads + 16B stores
    #pragma unroll
    for (int mf = 0; mf < 4; mf++)
      #pragma unroll
      for (int nf = 0; nf < 4; nf++)
        #pragma unroll
        for (int rg = 0; rg < 4; rg++)
          smem[(wr * 64 + mf * 16 + lq * 4 + rg) * 136 + wc * 64 + nf * 16 + lr]
              = f2bf(acc[mf][nf][rg]);
    __syncthreads();
    if (which == 3){
      #pragma unroll
      for (int p = 0; p < 8; p++){
        const int cid = p * 256 + tid;
        const int lrow = cid >> 4, cg = cid & 15;
        short8 vv = *(const short8*)(smem + lrow * 136 + cg * 8);
        *(short8*)(rbb + (size_t)(m0 + lrow) * 1024 + o0 + cg * 8) = vv;
      }
    } else {
      unsigned short* dst = (which == 0) ? qb : kb;
      #pragma unroll
      for (int p = 0; p < 8; p++){
        const int cid = p * 256 + tid;
        const int lrow = cid >> 4, cg = cid & 15;
        short8 vv = *(const short8*)(smem + lrow * 136 + cg * 8);
        const int rowi = m0 + lrow;
        const int s = rowi >> 4, bb = rowi & 15;
        const int o = o0 + cg * 8;
        const int bh = bb * 16 + (o >> 6), d = o & 63;
        *(short8*)(dst + ((size_t)bh * 512 + s) * 64 + d) = vv;
      }
    }
  }
}

// ---------------- fused attention ----------------
// 32 q-rows/block, 4 waves, 4096 blocks; bf16 out.
__global__ __launch_bounds__(256, 4) void attn_kernel(
    const unsigned short* __restrict__ qg, const unsigned short* __restrict__ kg,
    const unsigned short* __restrict__ vt,
    const unsigned char* __restrict__ mbits, const unsigned char* __restrict__ wbits,
    unsigned short* __restrict__ outp)
{
  __shared__ __align__(16) unsigned short sE[32 * 520];
  __shared__ float sfin[32];
  const int bid = ((blockIdx.x & 7) << 9) | (blockIdx.x >> 3);  // XCD swizzle (4096 = 8*512)
  const int qt = bid & 15, h = (bid >> 4) & 15, b = bid >> 8;   // qt-fastest: K/V L2 reuse
  const int tid = threadIdx.x, w = tid >> 6, l = tid & 63;
  const int lr = l & 15, lq = l >> 4;
  const int bh = b * 16 + h;
  const unsigned short* qp = qg + ((size_t)bh * 512 + qt * 32) * 64;
  const unsigned short* kp = kg + (size_t)bh * 512 * 64;
  const unsigned short* vp = vt + (size_t)bh * 64 * 512;

  const unsigned char* mrb = mbits + ((size_t)(b * 512 + qt * 32)) * 64;
  const unsigned char* wrb = wbits + ((size_t)(b * 512 + qt * 32)) * 64;
  unsigned int mby[2][4], wby[2][4];
  #pragma unroll
  for (int g = 0; g < 2; g++)
    #pragma unroll
    for (int rr = 0; rr < 4; rr++){
      mby[g][rr] = mrb[(g * 16 + w * 4 + rr) * 64 + l];
      wby[g][rr] = wrb[(g * 16 + w * 4 + rr) * 64 + l];
    }

  // ---- Phase A: QK^T on 128-col k-slice for 2 q-subtiles (indep chains) ----
  short8 qa[2][2];
  #pragma unroll
  for (int t = 0; t < 2; t++){
    qa[t][0] = *(const short8*)(qp + (t * 16 + lr) * 64 + lq * 8);
    qa[t][1] = *(const short8*)(qp + (t * 16 + lr) * 64 + 32 + lq * 8);
  }
  const float CEXP = 0.18033688011112042f;   // 0.125 * log2(e)
  #pragma unroll
  for (int kf = 0; kf < 8; kf++){
    const unsigned short* kr = kp + (size_t)(w * 128 + kf * 16 + lr) * 64;
    short8 k0 = *(const short8*)(kr + lq * 8);
    short8 k1 = *(const short8*)(kr + 32 + lq * 8);
    f32x4 a0 = {}, a1 = {};
    a0 = MFMA_BF16(qa[0][0], k0, a0);
    a1 = MFMA_BF16(qa[1][0], k0, a1);
    a0 = MFMA_BF16(qa[0][1], k1, a0);
    a1 = MFMA_BF16(qa[1][1], k1, a1);
    const int col = w * 128 + kf * 16 + lr;
    #pragma unroll
    for (int t = 0; t < 2; t++){
      f32x4 a = t ? a1 : a0;
      float e0 = __builtin_amdgcn_exp2f(a[0] * CEXP);
      float e1 = __builtin_amdgcn_exp2f(a[1] * CEXP);
      float e2 = __builtin_amdgcn_exp2f(a[2] * CEXP);
      float e3 = __builtin_amdgcn_exp2f(a[3] * CEXP);
      unsigned int p01 = cvtpk(e0, e1), p23 = cvtpk(e2, e3);
      const int row = t * 16 + lq * 4;
      sE[(row    ) * 520 + col] = (unsigned short)(p01 & 0xFFFFu);
      sE[(row + 1) * 520 + col] = (unsigned short)(p01 >> 16);
      sE[(row + 2) * 520 + col] = (unsigned short)(p23 & 0xFFFFu);
      sE[(row + 3) * 520 + col] = (unsigned short)(p23 >> 16);
    }
  }
  __syncthreads();

  // ---- Phase B: double masked softmax, 2 groups x 4 interleaved rows ----
  #pragma unroll
  for (int g = 0; g < 2; g++){
    const int row0 = g * 16 + w * 4;
    uint4 ev[4];
    #pragma unroll
    for (int rr = 0; rr < 4; rr++)
      ev[rr] = *(const uint4*)(sE + (row0 + rr) * 520 + l * 8);

    float em[4][8]; float z1[4];
    #pragma unroll
    for (int rr = 0; rr < 4; rr++){
      float e1[8];
      unpack8(ev[rr], e1);
      const unsigned int mb = mby[g][rr];
      float z = 0.f;
      #pragma unroll
      for (int j = 0; j < 8; j++){
        em[rr][j] = ((mb >> j) & 1u) ? e1[j] : 0.f;
        z += em[rr][j];
      }
      z1[rr] = z;
    }
    #pragma unroll
    for (int m = 32; m; m >>= 1){
      #pragma unroll
      for (int rr = 0; rr < 4; rr++) z1[rr] += __shfl_xor(z1[rr], m, 64);
    }
    float e2[4][8]; float z2[4];
    #pragma unroll
    for (int rr = 0; rr < 4; rr++){
      const float i1L = 1.4426950408889634f / z1[rr];
      const unsigned int wv = wby[g][rr];
      float z = 0.f;
      #pragma unroll
      for (int j = 0; j < 8; j++){
        float t = __builtin_amdgcn_exp2f(em[rr][j] * i1L);
        e2[rr][j] = ((wv >> j) & 1u) ? t : 0.f;
        z += e2[rr][j];
      }
      z2[rr] = z;
    }
    #pragma unroll
    for (int m = 32; m; m >>= 1){
      #pragma unroll
      for (int rr = 0; rr < 4; rr++) z2[rr] += __shfl_xor(z2[rr], m, 64);
    }
    #pragma unroll
    for (int rr = 0; rr < 4; rr++){
      uint4 o;
      o.x = cvtpk(e2[rr][0], e2[rr][1]); o.y = cvtpk(e2[rr][2], e2[rr][3]);
      o.z = cvtpk(e2[rr][4], e2[rr][5]); o.w = cvtpk(e2[rr][6], e2[rr][7]);
      *(uint4*)(sE + (row0 + rr) * 520 + l * 8) = o;
      if (l == 0) sfin[row0 + rr] = 1.f / (z2[rr] + 1e-10f);
    }
  }
  __syncthreads();

  // ---- Phase C: 2 po chains sharing each V frag; d-frag [16w,16w+16) ----
  {
    f32x4 po0 = {}, po1 = {};
    #pragma unroll
    for (int ks = 0; ks < 16; ks++){
      short8 vf = *(const short8*)(vp + (size_t)(w * 16 + lr) * 512 + ks * 32 + lq * 8);
      short8 af0 = *(const short8*)(sE + (     lr) * 520 + ks * 32 + lq * 8);
      short8 af1 = *(const short8*)(sE + (16 + lr) * 520 + ks * 32 + lq * 8);
      po0 = MFMA_BF16(af0, vf, po0);
      po1 = MFMA_BF16(af1, vf, po1);
    }
    #pragma unroll
    for (int rg = 0; rg < 4; rg++){
      const int r0 = lq * 4 + rg;
      outp[((size_t)(qt * 32 + r0) * 16 + b) * 1024 + h * 64 + w * 16 + lr]
          = f2bf(po0[rg] * sfin[r0]);
      outp[((size_t)(qt * 32 + 16 + r0) * 16 + b) * 1024 + h * 64 + w * 16 + lr]
          = f2bf(po1[rg] * sfin[16 + r0]);
    }
  }
}

// ---------------- gate + mix ----------------
__global__ __launch_bounds__(256) void gate_kernel(
    const unsigned short* __restrict__ outp, const unsigned short* __restrict__ rbb,
    const float* __restrict__ wba, const float* __restrict__ wbb,
    float* __restrict__ y)
{
  const int t = blockIdx.x * 4 + (threadIdx.x >> 6);
  const int l = threadIdx.x & 63;
  const unsigned short* o = outp + (size_t)t * 1024;
  const unsigned short* r = rbb + (size_t)t * 1024;
  float ov[16], rv[16];
  float acc = 0.f;
  #pragma unroll
  for (int j = 0; j < 16; j++){
    const int e = j * 64 + l;
    ov[j] = __uint_as_float((unsigned int)o[e] << 16);
    rv[j] = __uint_as_float((unsigned int)r[e] << 16);
    acc += ov[j] * wba[e] + rv[j] * wbb[e];
  }
  const float dot = wred_sum(acc);
  const float g = 1.f / (1.f + __builtin_amdgcn_exp2f(-dot * 1.4426950408889634f));
  float* yo = y + (size_t)t * 1024;
  #pragma unroll
  for (int j = 0; j < 16; j++){
    const int e = j * 64 + l;
    yo[e] = g * rv[j] + (1.f - g) * ov[j];
  }
}

// ---------------- launch ----------------
extern "C" void kernel_launch(void* const* d_in, const int* in_sizes, int n_in,
                              void* d_out, int out_size, void* d_ws, size_t ws_size,
                              hipStream_t stream)
{
  (void)in_sizes; (void)n_in; (void)out_size; (void)ws_size;
  const float* x   = (const float*)d_in[0];
  const int* mask  = (const int*)d_in[1];
  const int* wmask = (const int*)d_in[2];
  const float* Wq  = (const float*)d_in[3];
  const float* Wk  = (const float*)d_in[4];
  const float* Wv  = (const float*)d_in[5];
  const float* Ws  = (const float*)d_in[6];
  const float* Wb  = (const float*)d_in[7];

  char* ws = (char*)d_ws;
  unsigned short* xbf = (unsigned short*)ws; ws += 16777216;
  unsigned short* bm  = (unsigned short*)ws; ws += 8388608;
  unsigned short* qb  = (unsigned short*)ws; ws += 16777216;
  unsigned short* kb  = (unsigned short*)ws; ws += 16777216;
  unsigned short* vT  = (unsigned short*)ws; ws += 16777216;
  unsigned short* rbb = (unsigned short*)ws; ws += 16777216;
  unsigned short* op  = (unsigned short*)ws; ws += 16777216;
  float* wba = (float*)ws; ws += 4096;
  float* wbb = (float*)ws; ws += 4096;
  unsigned long long* mb64 = (unsigned long long*)xbf;
  unsigned long long* wb64 = (unsigned long long*)bm;

  cvt_x_kernel<<<8192, 256, 0, stream>>>(x, xbf);
  cvt_w_kernel<<<4096, 256, 0, stream>>>(Wq, Wk, Wv, Ws, bm);
  wb_prep_kernel<<<4, 256, 0, stream>>>(Wb, wba, wbb);
  gemm_proj_kernel<<<2048, 256, 0, stream>>>(xbf, bm, qb, kb, vT, rbb);
  mask_prep_kernel<<<16384, 256, 0, stream>>>(mask, wmask, mb64, wb64);
  attn_kernel<<<4096, 256, 0, stream>>>(qb, kb, vT,
      (const unsigned char*)mb64, (const unsigned char*)wb64, op);
  gate_kernel<<<2048, 256, 0, stream>>>(op, rbb, wba, wbb, (float*)d_out);
}

// Round 10
// 185.385 us; speedup vs baseline: 1.0883x; 1.0883x over previous
//
#include <hip/hip_runtime.h>
#include <hip/hip_bf16.h>
#include <stdint.h>

typedef __attribute__((ext_vector_type(8))) short short8;
typedef __attribute__((ext_vector_type(4))) float f32x4;
typedef __attribute__((ext_vector_type(4))) unsigned short ushort4v;

#define MFMA_BF16(a,b,c) __builtin_amdgcn_mfma_f32_16x16x32_bf16((a),(b),(c),0,0,0)

static __device__ __forceinline__ unsigned short f2bf(float f){
  union { float fv; unsigned int u; } c; c.fv = f;
  unsigned int u = c.u;
  return (unsigned short)((u + 0x7fffu + ((u >> 16) & 1u)) >> 16);
}

static __device__ __forceinline__ unsigned int cvtpk(float a, float b){
  unsigned int r;
  asm("v_cvt_pk_bf16_f32 %0, %1, %2" : "=v"(r) : "v"(a), "v"(b));
  return r;
}

static __device__ __forceinline__ void gload_lds16(const void* g, void* l){
  __builtin_amdgcn_global_load_lds(
      (const __attribute__((address_space(1))) void*)g,
      (__attribute__((address_space(3))) void*)l, 16, 0, 0);
}

static __device__ __forceinline__ float wred_sum(float v){
  #pragma unroll
  for (int m = 32; m; m >>= 1) v += __shfl_xor(v, m, 64);
  return v;
}

static __device__ __forceinline__ void unpack8(uint4 u, float* f){
  f[0] = __uint_as_float(u.x << 16); f[1] = __uint_as_float(u.x & 0xFFFF0000u);
  f[2] = __uint_as_float(u.y << 16); f[3] = __uint_as_float(u.y & 0xFFFF0000u);
  f[4] = __uint_as_float(u.z << 16); f[5] = __uint_as_float(u.z & 0xFFFF0000u);
  f[6] = __uint_as_float(u.w << 16); f[7] = __uint_as_float(u.w & 0xFFFF0000u);
}

// ---------------- conversion kernels ----------------
__global__ __launch_bounds__(256) void cvt_x_kernel(const float* __restrict__ x,
                                                    unsigned short* __restrict__ o){
  int i = blockIdx.x * 256 + threadIdx.x;
  float4 f = ((const float4*)x)[i];
  ushort4v r;
  r[0] = f2bf(f.x); r[1] = f2bf(f.y); r[2] = f2bf(f.z); r[3] = f2bf(f.w);
  ((ushort4v*)o)[i] = r;
}

__global__ __launch_bounds__(256) void cvt_w_kernel(const float* __restrict__ Wq,
                                                    const float* __restrict__ Wk,
                                                    const float* __restrict__ Wv,
                                                    const float* __restrict__ Ws,
                                                    unsigned short* __restrict__ B){
  int i = blockIdx.x * 256 + threadIdx.x;
  int which = i >> 18;
  const float* src = (which == 0) ? Wq : (which == 1) ? Wk : (which == 2) ? Wv : Ws;
  float4 f = ((const float4*)src)[i & 262143];
  ushort4v r;
  r[0] = f2bf(f.x); r[1] = f2bf(f.y); r[2] = f2bf(f.z); r[3] = f2bf(f.w);
  ((ushort4v*)B)[i] = r;
}

__global__ void wb_prep_kernel(const float* __restrict__ Wb,
                               float* __restrict__ wba, float* __restrict__ wbb){
  int e = blockIdx.x * 256 + threadIdx.x;
  if (e < 1024){
    wba[e] = Wb[e]        + Wb[2048 + e];
    wbb[e] = Wb[1024 + e] - Wb[2048 + e];
  }
}

// masks -> bit planes via ballot
__global__ __launch_bounds__(256) void mask_prep_kernel(
    const int* __restrict__ m, const int* __restrict__ wm,
    unsigned long long* __restrict__ mb, unsigned long long* __restrict__ wb)
{
  const size_t i = (size_t)blockIdx.x * 256 + threadIdx.x;
  const int a = m[i];
  const int c = wm[i];
  unsigned long long ba = __ballot(a != 0);
  unsigned long long bc = __ballot(c != 0);
  if ((threadIdx.x & 63) == 0){
    mb[i >> 6] = ba;
    wb[i >> 6] = bc;
  }
}

// ---------------- fused projection GEMM (pipelined, T3/T4/T5) ----------------
// 256x128 tile, 8 waves (4M x 2N, 64x64/wave), BK=64, 3 LDS bufs, lookahead-2.
// Per iter: vmcnt(6) + one raw barrier; stage tile t+2 while computing tile t.
// LDS reads XOR-chunk-swizzled (source pre-swizzle, read-side same XOR).
__global__ __launch_bounds__(512, 1) void gemm_proj_kernel(
    const unsigned short* __restrict__ X, const unsigned short* __restrict__ B,
    unsigned short* __restrict__ qb, unsigned short* __restrict__ kb,
    unsigned short* __restrict__ vT, unsigned short* __restrict__ rbb)
{
  __shared__ __align__(16) unsigned short smem[73728];   // 3 x 48KB
  const int tid = threadIdx.x;
  const int w = tid >> 6, l = tid & 63;
  const int lr = l & 15, lq = l >> 4;
  const int wm = w >> 1, wn = w & 1;           // wave C: rows wm*64.., cols wn*64..
  const int bid = ((blockIdx.x & 7) << 7) | (blockIdx.x >> 3);   // 1024 = 8*128
  const int mt = bid >> 5, nt = bid & 31;      // mt-outer: 4 mt/XCD -> A slice 2MB
  const int m0 = mt * 256, n0 = nt * 128;
  const int lrow8 = l >> 3, lc = l & 7;

  f32x4 acc[4][4] = {};

  // stage tile T (k = T*64) into buf T%3: A 256x64 (segs 0..31), B 128x64 (segs 0..15)
  // seg = 1KB = 8 rows; lane L -> row seg*8 + (L>>3), phys slot L&7 holds logical
  // chunk (L&7)^(row&7)  => read side uses the same XOR.
  #define STAGE(T) { \
    const int bufo_ = ((T) % 3) * 24576; \
    const int kk_ = (T) * 64; \
    _Pragma("unroll") \
    for (int j = 0; j < 4; j++){ \
      const int seg = w + j * 8; \
      const int r = seg * 8 + lrow8; \
      gload_lds16(X + (size_t)(m0 + r) * 1024 + kk_ + ((lc ^ (r & 7)) * 8), \
                  smem + bufo_ + seg * 512); \
    } \
    _Pragma("unroll") \
    for (int j = 0; j < 2; j++){ \
      const int seg = w + j * 8; \
      const int r = seg * 8 + lrow8; \
      gload_lds16(B + (size_t)(n0 + r) * 1024 + kk_ + ((lc ^ (r & 7)) * 8), \
                  smem + bufo_ + 16384 + seg * 512); \
    } }

  #define COMPUTE(T) { \
    const int bo_ = ((T) % 3) * 24576; \
    _Pragma("unroll") \
    for (int subk = 0; subk < 2; subk++){ \
      short8 av[4], bv[4]; \
      const int pc = (((subk * 4 + lq) ^ (lr & 7)) * 8); \
      _Pragma("unroll") \
      for (int mf = 0; mf < 4; mf++) \
        av[mf] = *(const short8*)(smem + bo_ + (wm * 64 + mf * 16 + lr) * 64 + pc); \
      _Pragma("unroll") \
      for (int nf = 0; nf < 4; nf++) \
        bv[nf] = *(const short8*)(smem + bo_ + 16384 + (wn * 64 + nf * 16 + lr) * 64 + pc); \
      __builtin_amdgcn_s_setprio(1); \
      _Pragma("unroll") \
      for (int mf = 0; mf < 4; mf++) \
        _Pragma("unroll") \
        for (int nf = 0; nf < 4; nf++) \
          acc[mf][nf] = MFMA_BF16(av[mf], bv[nf], acc[mf][nf]); \
      __builtin_amdgcn_s_setprio(0); \
    } }

  STAGE(0)
  STAGE(1)

  for (int t = 0; t < 15; t++){
    asm volatile("s_waitcnt vmcnt(6)" ::: "memory");  // own tile-t loads done
    __builtin_amdgcn_s_barrier();                      // all waves' loads done; fences buf reuse
    if (t < 14) STAGE(t + 2)
    COMPUTE(t)
  }
  asm volatile("s_waitcnt vmcnt(0)" ::: "memory");
  __builtin_amdgcn_s_barrier();
  COMPUTE(15)

  // ---- epilogue: LDS-staged coalesced stores ----
  const int which = nt >> 3;
  const int o0 = (nt & 7) * 128;
  if (which == 2){
    // v transposed: smem[128 cols][264 row-pad], single pass
    __syncthreads();
    #pragma unroll
    for (int mf = 0; mf < 4; mf++)
      #pragma unroll
      for (int nf = 0; nf < 4; nf++){
        const int c = wn * 64 + nf * 16 + lr;
        const int r0v = wm * 64 + mf * 16 + lq * 4;
        uint2 pk;
        pk.x = cvtpk(acc[mf][nf][0], acc[mf][nf][1]);
        pk.y = cvtpk(acc[mf][nf][2], acc[mf][nf][3]);
        *(uint2*)(smem + c * 264 + r0v) = pk;
      }
    __syncthreads();
    #pragma unroll
    for (int p = 0; p < 8; p++){
      const int cid = p * 512 + tid;        // 4096 chunks: c(128) x bb(16) x sh(2)
      const int c = cid >> 5, bb = (cid >> 1) & 15, sh = cid & 1;
      short8 st;
      #pragma unroll
      for (int j = 0; j < 8; j++) st[j] = (short)smem[c * 264 + (sh * 8 + j) * 16 + bb];
      const int o = o0 + c;
      const int bh = bb * 16 + (o >> 6), d = o & 63;
      *(short8*)(vT + ((size_t)bh * 64 + d) * 512 + mt * 16 + sh * 8) = st;
    }
  } else {
    // q/k/r: two row-half passes through smem[128][136]
    #pragma unroll
    for (int h2 = 0; h2 < 2; h2++){
      __syncthreads();
      if ((wm >> 1) == h2){
        #pragma unroll
        for (int mf = 0; mf < 4; mf++)
          #pragma unroll
          for (int nf = 0; nf < 4; nf++)
            #pragma unroll
            for (int rg = 0; rg < 4; rg++)
              smem[((wm & 1) * 64 + mf * 16 + lq * 4 + rg) * 136 + wn * 64 + nf * 16 + lr]
                  = f2bf(acc[mf][nf][rg]);
      }
      __syncthreads();
      if (which == 3){
        #pragma unroll
        for (int p = 0; p < 4; p++){
          const int cid = p * 512 + tid;
          const int lrow = cid >> 4, cg = cid & 15;
          short8 vv = *(const short8*)(smem + lrow * 136 + cg * 8);
          *(short8*)(rbb + (size_t)(m0 + h2 * 128 + lrow) * 1024 + o0 + cg * 8) = vv;
        }
      } else {
        unsigned short* dst = (which == 0) ? qb : kb;
        #pragma unroll
        for (int p = 0; p < 4; p++){
          const int cid = p * 512 + tid;
          const int lrow = cid >> 4, cg = cid & 15;
          short8 vv = *(const short8*)(smem + lrow * 136 + cg * 8);
          const int rowi = m0 + h2 * 128 + lrow;
          const int s = rowi >> 4, bb = rowi & 15;
          const int o = o0 + cg * 8;
          const int bh = bb * 16 + (o >> 6), d = o & 63;
          *(short8*)(dst + ((size_t)bh * 512 + s) * 64 + d) = vv;
        }
      }
    }
  }
  #undef STAGE
  #undef COMPUTE
}

// ---------------- fused attention ----------------
// 32 q-rows/block, 4 waves, 4096 blocks; bf16 out.
__global__ __launch_bounds__(256, 4) void attn_kernel(
    const unsigned short* __restrict__ qg, const unsigned short* __restrict__ kg,
    const unsigned short* __restrict__ vt,
    const unsigned char* __restrict__ mbits, const unsigned char* __restrict__ wbits,
    unsigned short* __restrict__ outp)
{
  __shared__ __align__(16) unsigned short sE[32 * 520];
  __shared__ float sfin[32];
  const int bid = ((blockIdx.x & 7) << 9) | (blockIdx.x >> 3);  // XCD swizzle (4096 = 8*512)
  const int qt = bid & 15, h = (bid >> 4) & 15, b = bid >> 8;   // qt-fastest: K/V L2 reuse
  const int tid = threadIdx.x, w = tid >> 6, l = tid & 63;
  const int lr = l & 15, lq = l >> 4;
  const int bh = b * 16 + h;
  const unsigned short* qp = qg + ((size_t)bh * 512 + qt * 32) * 64;
  const unsigned short* kp = kg + (size_t)bh * 512 * 64;
  const unsigned short* vp = vt + (size_t)bh * 64 * 512;

  const unsigned char* mrb = mbits + ((size_t)(b * 512 + qt * 32)) * 64;
  const unsigned char* wrb = wbits + ((size_t)(b * 512 + qt * 32)) * 64;
  unsigned int mby[2][4], wby[2][4];
  #pragma unroll
  for (int g = 0; g < 2; g++)
    #pragma unroll
    for (int rr = 0; rr < 4; rr++){
      mby[g][rr] = mrb[(g * 16 + w * 4 + rr) * 64 + l];
      wby[g][rr] = wrb[(g * 16 + w * 4 + rr) * 64 + l];
    }

  // ---- Phase A: QK^T on 128-col k-slice for 2 q-subtiles (indep chains) ----
  short8 qa[2][2];
  #pragma unroll
  for (int t = 0; t < 2; t++){
    qa[t][0] = *(const short8*)(qp + (t * 16 + lr) * 64 + lq * 8);
    qa[t][1] = *(const short8*)(qp + (t * 16 + lr) * 64 + 32 + lq * 8);
  }
  const float CEXP = 0.18033688011112042f;   // 0.125 * log2(e)
  #pragma unroll
  for (int kf = 0; kf < 8; kf++){
    const unsigned short* kr = kp + (size_t)(w * 128 + kf * 16 + lr) * 64;
    short8 k0 = *(const short8*)(kr + lq * 8);
    short8 k1 = *(const short8*)(kr + 32 + lq * 8);
    f32x4 a0 = {}, a1 = {};
    a0 = MFMA_BF16(qa[0][0], k0, a0);
    a1 = MFMA_BF16(qa[1][0], k0, a1);
    a0 = MFMA_BF16(qa[0][1], k1, a0);
    a1 = MFMA_BF16(qa[1][1], k1, a1);
    const int col = w * 128 + kf * 16 + lr;
    #pragma unroll
    for (int t = 0; t < 2; t++){
      f32x4 a = t ? a1 : a0;
      float e0 = __builtin_amdgcn_exp2f(a[0] * CEXP);
      float e1 = __builtin_amdgcn_exp2f(a[1] * CEXP);
      float e2 = __builtin_amdgcn_exp2f(a[2] * CEXP);
      float e3 = __builtin_amdgcn_exp2f(a[3] * CEXP);
      unsigned int p01 = cvtpk(e0, e1), p23 = cvtpk(e2, e3);
      const int row = t * 16 + lq * 4;
      sE[(row    ) * 520 + col] = (unsigned short)(p01 & 0xFFFFu);
      sE[(row + 1) * 520 + col] = (unsigned short)(p01 >> 16);
      sE[(row + 2) * 520 + col] = (unsigned short)(p23 & 0xFFFFu);
      sE[(row + 3) * 520 + col] = (unsigned short)(p23 >> 16);
    }
  }
  __syncthreads();

  // ---- Phase B: double masked softmax, 2 groups x 4 interleaved rows ----
  #pragma unroll
  for (int g = 0; g < 2; g++){
    const int row0 = g * 16 + w * 4;
    uint4 ev[4];
    #pragma unroll
    for (int rr = 0; rr < 4; rr++)
      ev[rr] = *(const uint4*)(sE + (row0 + rr) * 520 + l * 8);

    float em[4][8]; float z1[4];
    #pragma unroll
    for (int rr = 0; rr < 4; rr++){
      float e1[8];
      unpack8(ev[rr], e1);
      const unsigned int mb = mby[g][rr];
      float z = 0.f;
      #pragma unroll
      for (int j = 0; j < 8; j++){
        em[rr][j] = ((mb >> j) & 1u) ? e1[j] : 0.f;
        z += em[rr][j];
      }
      z1[rr] = z;
    }
    #pragma unroll
    for (int m = 32; m; m >>= 1){
      #pragma unroll
      for (int rr = 0; rr < 4; rr++) z1[rr] += __shfl_xor(z1[rr], m, 64);
    }
    float e2[4][8]; float z2[4];
    #pragma unroll
    for (int rr = 0; rr < 4; rr++){
      const float i1L = 1.4426950408889634f / z1[rr];
      const unsigned int wv = wby[g][rr];
      float z = 0.f;
      #pragma unroll
      for (int j = 0; j < 8; j++){
        float t = __builtin_amdgcn_exp2f(em[rr][j] * i1L);
        e2[rr][j] = ((wv >> j) & 1u) ? t : 0.f;
        z += e2[rr][j];
      }
      z2[rr] = z;
    }
    #pragma unroll
    for (int m = 32; m; m >>= 1){
      #pragma unroll
      for (int rr = 0; rr < 4; rr++) z2[rr] += __shfl_xor(z2[rr], m, 64);
    }
    #pragma unroll
    for (int rr = 0; rr < 4; rr++){
      uint4 o;
      o.x = cvtpk(e2[rr][0], e2[rr][1]); o.y = cvtpk(e2[rr][2], e2[rr][3]);
      o.z = cvtpk(e2[rr][4], e2[rr][5]); o.w = cvtpk(e2[rr][6], e2[rr][7]);
      *(uint4*)(sE + (row0 + rr) * 520 + l * 8) = o;
      if (l == 0) sfin[row0 + rr] = 1.f / (z2[rr] + 1e-10f);
    }
  }
  __syncthreads();

  // ---- Phase C: 2 po chains sharing each V frag; d-frag [16w,16w+16) ----
  {
    f32x4 po0 = {}, po1 = {};
    #pragma unroll
    for (int ks = 0; ks < 16; ks++){
      short8 vf = *(const short8*)(vp + (size_t)(w * 16 + lr) * 512 + ks * 32 + lq * 8);
      short8 af0 = *(const short8*)(sE + (     lr) * 520 + ks * 32 + lq * 8);
      short8 af1 = *(const short8*)(sE + (16 + lr) * 520 + ks * 32 + lq * 8);
      po0 = MFMA_BF16(af0, vf, po0);
      po1 = MFMA_BF16(af1, vf, po1);
    }
    #pragma unroll
    for (int rg = 0; rg < 4; rg++){
      const int r0 = lq * 4 + rg;
      outp[((size_t)(qt * 32 + r0) * 16 + b) * 1024 + h * 64 + w * 16 + lr]
          = f2bf(po0[rg] * sfin[r0]);
      outp[((size_t)(qt * 32 + 16 + r0) * 16 + b) * 1024 + h * 64 + w * 16 + lr]
          = f2bf(po1[rg] * sfin[16 + r0]);
    }
  }
}

// ---------------- gate + mix ----------------
__global__ __launch_bounds__(256) void gate_kernel(
    const unsigned short* __restrict__ outp, const unsigned short* __restrict__ rbb,
    const float* __restrict__ wba, const float* __restrict__ wbb,
    float* __restrict__ y)
{
  const int t = blockIdx.x * 4 + (threadIdx.x >> 6);
  const int l = threadIdx.x & 63;
  const unsigned short* o = outp + (size_t)t * 1024;
  const unsigned short* r = rbb + (size_t)t * 1024;
  float ov[16], rv[16];
  float acc = 0.f;
  #pragma unroll
  for (int j = 0; j < 16; j++){
    const int e = j * 64 + l;
    ov[j] = __uint_as_float((unsigned int)o[e] << 16);
    rv[j] = __uint_as_float((unsigned int)r[e] << 16);
    acc += ov[j] * wba[e] + rv[j] * wbb[e];
  }
  const float dot = wred_sum(acc);
  const float g = 1.f / (1.f + __builtin_amdgcn_exp2f(-dot * 1.4426950408889634f));
  float* yo = y + (size_t)t * 1024;
  #pragma unroll
  for (int j = 0; j < 16; j++){
    const int e = j * 64 + l;
    yo[e] = g * rv[j] + (1.f - g) * ov[j];
  }
}

// ---------------- launch ----------------
extern "C" void kernel_launch(void* const* d_in, const int* in_sizes, int n_in,
                              void* d_out, int out_size, void* d_ws, size_t ws_size,
                              hipStream_t stream)
{
  (void)in_sizes; (void)n_in; (void)out_size; (void)ws_size;
  const float* x   = (const float*)d_in[0];
  const int* mask  = (const int*)d_in[1];
  const int* wmask = (const int*)d_in[2];
  const float* Wq  = (const float*)d_in[3];
  const float* Wk  = (const float*)d_in[4];
  const float* Wv  = (const float*)d_in[5];
  const float* Ws  = (const float*)d_in[6];
  const float* Wb  = (const float*)d_in[7];

  char* ws = (char*)d_ws;
  unsigned short* xbf = (unsigned short*)ws; ws += 16777216;
  unsigned short* bm  = (unsigned short*)ws; ws += 8388608;
  unsigned short* qb  = (unsigned short*)ws; ws += 16777216;
  unsigned short* kb  = (unsigned short*)ws; ws += 16777216;
  unsigned short* vT  = (unsigned short*)ws; ws += 16777216;
  unsigned short* rbb = (unsigned short*)ws; ws += 16777216;
  unsigned short* op  = (unsigned short*)ws; ws += 16777216;
  float* wba = (float*)ws; ws += 4096;
  float* wbb = (float*)ws; ws += 4096;
  unsigned long long* mb64 = (unsigned long long*)xbf;
  unsigned long long* wb64 = (unsigned long long*)bm;

  cvt_x_kernel<<<8192, 256, 0, stream>>>(x, xbf);
  cvt_w_kernel<<<4096, 256, 0, stream>>>(Wq, Wk, Wv, Ws, bm);
  wb_prep_kernel<<<4, 256, 0, stream>>>(Wb, wba, wbb);
  gemm_proj_kernel<<<1024, 512, 0, stream>>>(xbf, bm, qb, kb, vT, rbb);
  mask_prep_kernel<<<16384, 256, 0, stream>>>(mask, wmask, mb64, wb64);
  attn_kernel<<<4096, 256, 0, stream>>>(qb, kb, vT,
      (const unsigned char*)mb64, (const unsigned char*)wb64, op);
  gate_kernel<<<2048, 256, 0, stream>>>(op, rbb, wba, wbb, (float*)d_out);
}

// Round 11
// 177.808 us; speedup vs baseline: 1.1347x; 1.0426x over previous
//
#include <hip/hip_runtime.h>
#include <hip/hip_bf16.h>
#include <stdint.h>

typedef __attribute__((ext_vector_type(8))) short short8;
typedef __attribute__((ext_vector_type(4))) float f32x4;
typedef __attribute__((ext_vector_type(4))) unsigned short ushort4v;

#define MFMA_BF16(a,b,c) __builtin_amdgcn_mfma_f32_16x16x32_bf16((a),(b),(c),0,0,0)

static __device__ __forceinline__ unsigned short f2bf(float f){
  union { float fv; unsigned int u; } c; c.fv = f;
  unsigned int u = c.u;
  return (unsigned short)((u + 0x7fffu + ((u >> 16) & 1u)) >> 16);
}

static __device__ __forceinline__ unsigned int cvtpk(float a, float b){
  unsigned int r;
  asm("v_cvt_pk_bf16_f32 %0, %1, %2" : "=v"(r) : "v"(a), "v"(b));
  return r;
}

static __device__ __forceinline__ void gload_lds16(const void* g, void* l){
  __builtin_amdgcn_global_load_lds(
      (const __attribute__((address_space(1))) void*)g,
      (__attribute__((address_space(3))) void*)l, 16, 0, 0);
}

static __device__ __forceinline__ float wred_sum(float v){
  #pragma unroll
  for (int m = 32; m; m >>= 1) v += __shfl_xor(v, m, 64);
  return v;
}

static __device__ __forceinline__ void unpack8(uint4 u, float* f){
  f[0] = __uint_as_float(u.x << 16); f[1] = __uint_as_float(u.x & 0xFFFF0000u);
  f[2] = __uint_as_float(u.y << 16); f[3] = __uint_as_float(u.y & 0xFFFF0000u);
  f[4] = __uint_as_float(u.z << 16); f[5] = __uint_as_float(u.z & 0xFFFF0000u);
  f[6] = __uint_as_float(u.w << 16); f[7] = __uint_as_float(u.w & 0xFFFF0000u);
}

// ---------------- conversion kernels ----------------
__global__ __launch_bounds__(256) void cvt_x_kernel(const float* __restrict__ x,
                                                    unsigned short* __restrict__ o){
  int i = blockIdx.x * 256 + threadIdx.x;
  float4 f = ((const float4*)x)[i];
  ushort4v r;
  r[0] = f2bf(f.x); r[1] = f2bf(f.y); r[2] = f2bf(f.z); r[3] = f2bf(f.w);
  ((ushort4v*)o)[i] = r;
}

__global__ __launch_bounds__(256) void cvt_w_kernel(const float* __restrict__ Wq,
                                                    const float* __restrict__ Wk,
                                                    const float* __restrict__ Wv,
                                                    const float* __restrict__ Ws,
                                                    unsigned short* __restrict__ B){
  int i = blockIdx.x * 256 + threadIdx.x;
  int which = i >> 18;
  const float* src = (which == 0) ? Wq : (which == 1) ? Wk : (which == 2) ? Wv : Ws;
  float4 f = ((const float4*)src)[i & 262143];
  ushort4v r;
  r[0] = f2bf(f.x); r[1] = f2bf(f.y); r[2] = f2bf(f.z); r[3] = f2bf(f.w);
  ((ushort4v*)B)[i] = r;
}

__global__ void wb_prep_kernel(const float* __restrict__ Wb,
                               float* __restrict__ wba, float* __restrict__ wbb){
  int e = blockIdx.x * 256 + threadIdx.x;
  if (e < 1024){
    wba[e] = Wb[e]        + Wb[2048 + e];
    wbb[e] = Wb[1024 + e] - Wb[2048 + e];
  }
}

// masks -> bit planes via ballot
__global__ __launch_bounds__(256) void mask_prep_kernel(
    const int* __restrict__ m, const int* __restrict__ wm,
    unsigned long long* __restrict__ mb, unsigned long long* __restrict__ wb)
{
  const size_t i = (size_t)blockIdx.x * 256 + threadIdx.x;
  const int a = m[i];
  const int c = wm[i];
  unsigned long long ba = __ballot(a != 0);
  unsigned long long bc = __ballot(c != 0);
  if ((threadIdx.x & 63) == 0){
    mb[i >> 6] = ba;
    wb[i >> 6] = bc;
  }
}

// ---------------- fused projection GEMM (pipelined, phase-split) ----------------
// 256x128 tile, 8 waves (4M x 2N), BK=64, 3 LDS bufs, lookahead-2, counted vmcnt(6).
// Each iter = 2 phases: {8 ds_read frags || 3 stage loads -> lgkmcnt(0) -> 16 MFMA}.
// mt-fastest per-XCD ordering: B nt-slice (0.26MB) + A slice (2MB) stay L2-resident.
__global__ __launch_bounds__(512, 1) void gemm_proj_kernel(
    const unsigned short* __restrict__ X, const unsigned short* __restrict__ B,
    unsigned short* __restrict__ qb, unsigned short* __restrict__ kb,
    unsigned short* __restrict__ vT, unsigned short* __restrict__ rbb)
{
  __shared__ __align__(16) unsigned short smem[73728];   // 3 x 24KB tiles
  const int tid = threadIdx.x;
  const int w = tid >> 6, l = tid & 63;
  const int lr = l & 15, lq = l >> 4;
  const int wm = w >> 1, wn = w & 1;
  const int xcd = blockIdx.x & 7, o = blockIdx.x >> 3;           // o in [0,128)
  const int mt = xcd * 4 + (o & 3), nt = o >> 2;                 // mt-fastest in XCD
  const int m0 = mt * 256, n0 = nt * 128;
  const int lrow8 = l >> 3, lc = l & 7;

  f32x4 acc[4][4] = {};

  // stage half H (0: A segs j=0,1 + B seg j=0; 1: A segs j=2,3 + B seg j=1)
  #define STAGE_H(T, H) { \
    const int bufo_ = ((T) % 3) * 24576; \
    const int kk_ = (T) * 64; \
    _Pragma("unroll") \
    for (int j = (H) * 2; j < (H) * 2 + 2; j++){ \
      const int seg = w + j * 8; \
      const int r = seg * 8 + lrow8; \
      gload_lds16(X + (size_t)(m0 + r) * 1024 + kk_ + ((lc ^ (r & 7)) * 8), \
                  smem + bufo_ + seg * 512); \
    } \
    { \
      const int seg = w + (H) * 8; \
      const int r = seg * 8 + lrow8; \
      gload_lds16(B + (size_t)(n0 + r) * 1024 + kk_ + ((lc ^ (r & 7)) * 8), \
                  smem + bufo_ + 16384 + seg * 512); \
    } }

  // one phase: ds_read subk frags, optional stage half, lgkm fence, MFMA cluster
  #define PHASE(T, SUBK, DOSTAGE) { \
    const int bo_ = ((T) % 3) * 24576; \
    short8 av[4], bv[4]; \
    const int pc = ((((SUBK) * 4 + lq) ^ (lr & 7)) * 8); \
    _Pragma("unroll") \
    for (int mf = 0; mf < 4; mf++) \
      av[mf] = *(const short8*)(smem + bo_ + (wm * 64 + mf * 16 + lr) * 64 + pc); \
    _Pragma("unroll") \
    for (int nf = 0; nf < 4; nf++) \
      bv[nf] = *(const short8*)(smem + bo_ + 16384 + (wn * 64 + nf * 16 + lr) * 64 + pc); \
    if (DOSTAGE) STAGE_H((T) + 2, SUBK) \
    asm volatile("s_waitcnt lgkmcnt(0)" ::: "memory"); \
    __builtin_amdgcn_sched_barrier(0); \
    __builtin_amdgcn_s_setprio(1); \
    _Pragma("unroll") \
    for (int mf = 0; mf < 4; mf++) \
      _Pragma("unroll") \
      for (int nf = 0; nf < 4; nf++) \
        acc[mf][nf] = MFMA_BF16(av[mf], bv[nf], acc[mf][nf]); \
    __builtin_amdgcn_s_setprio(0); }

  STAGE_H(0, 0) STAGE_H(0, 1)
  STAGE_H(1, 0) STAGE_H(1, 1)

  for (int t = 0; t < 15; t++){
    asm volatile("s_waitcnt vmcnt(6)" ::: "memory");   // own tile-t loads done
    __builtin_amdgcn_s_barrier();                      // all waves ready; fences buf reuse
    const bool st = (t < 14);
    PHASE(t, 0, st)
    __builtin_amdgcn_s_barrier();
    PHASE(t, 1, st)
  }
  asm volatile("s_waitcnt vmcnt(0)" ::: "memory");
  __builtin_amdgcn_s_barrier();
  PHASE(15, 0, false)
  PHASE(15, 1, false)

  // ---- epilogue: LDS-staged coalesced stores ----
  const int which = nt >> 3;
  const int o0 = (nt & 7) * 128;
  if (which == 2){
    // v transposed: smem[128 cols][264 row-pad], single pass
    __syncthreads();
    #pragma unroll
    for (int mf = 0; mf < 4; mf++)
      #pragma unroll
      for (int nf = 0; nf < 4; nf++){
        const int c = wn * 64 + nf * 16 + lr;
        const int r0v = wm * 64 + mf * 16 + lq * 4;
        uint2 pk;
        pk.x = cvtpk(acc[mf][nf][0], acc[mf][nf][1]);
        pk.y = cvtpk(acc[mf][nf][2], acc[mf][nf][3]);
        *(uint2*)(smem + c * 264 + r0v) = pk;
      }
    __syncthreads();
    #pragma unroll
    for (int p = 0; p < 8; p++){
      const int cid = p * 512 + tid;        // 4096 chunks: c(128) x bb(16) x sh(2)
      const int c = cid >> 5, bb = (cid >> 1) & 15, sh = cid & 1;
      short8 st;
      #pragma unroll
      for (int j = 0; j < 8; j++) st[j] = (short)smem[c * 264 + (sh * 8 + j) * 16 + bb];
      const int oo = o0 + c;
      const int bh = bb * 16 + (oo >> 6), d = oo & 63;
      *(short8*)(vT + ((size_t)bh * 64 + d) * 512 + mt * 16 + sh * 8) = st;
    }
  } else {
    // q/k/r: two row-half passes through smem[128][136]
    #pragma unroll
    for (int h2 = 0; h2 < 2; h2++){
      __syncthreads();
      if ((wm >> 1) == h2){
        #pragma unroll
        for (int mf = 0; mf < 4; mf++)
          #pragma unroll
          for (int nf = 0; nf < 4; nf++)
            #pragma unroll
            for (int rg = 0; rg < 4; rg++)
              smem[((wm & 1) * 64 + mf * 16 + lq * 4 + rg) * 136 + wn * 64 + nf * 16 + lr]
                  = f2bf(acc[mf][nf][rg]);
      }
      __syncthreads();
      if (which == 3){
        #pragma unroll
        for (int p = 0; p < 4; p++){
          const int cid = p * 512 + tid;
          const int lrow = cid >> 4, cg = cid & 15;
          short8 vv = *(const short8*)(smem + lrow * 136 + cg * 8);
          *(short8*)(rbb + (size_t)(m0 + h2 * 128 + lrow) * 1024 + o0 + cg * 8) = vv;
        }
      } else {
        unsigned short* dst = (which == 0) ? qb : kb;
        #pragma unroll
        for (int p = 0; p < 4; p++){
          const int cid = p * 512 + tid;
          const int lrow = cid >> 4, cg = cid & 15;
          short8 vv = *(const short8*)(smem + lrow * 136 + cg * 8);
          const int rowi = m0 + h2 * 128 + lrow;
          const int s = rowi >> 4, bb = rowi & 15;
          const int oo = o0 + cg * 8;
          const int bh = bb * 16 + (oo >> 6), d = oo & 63;
          *(short8*)(dst + ((size_t)bh * 512 + s) * 64 + d) = vv;
        }
      }
    }
  }
  #undef STAGE_H
  #undef PHASE
}

// ---------------- fused attention ----------------
// 32 q-rows/block, 4 waves, 4096 blocks; bf16 out.
__global__ __launch_bounds__(256, 4) void attn_kernel(
    const unsigned short* __restrict__ qg, const unsigned short* __restrict__ kg,
    const unsigned short* __restrict__ vt,
    const unsigned char* __restrict__ mbits, const unsigned char* __restrict__ wbits,
    unsigned short* __restrict__ outp)
{
  __shared__ __align__(16) unsigned short sE[32 * 520];
  __shared__ float sfin[32];
  const int bid = ((blockIdx.x & 7) << 9) | (blockIdx.x >> 3);  // XCD swizzle (4096 = 8*512)
  const int qt = bid & 15, h = (bid >> 4) & 15, b = bid >> 8;   // qt-fastest: K/V L2 reuse
  const int tid = threadIdx.x, w = tid >> 6, l = tid & 63;
  const int lr = l & 15, lq = l >> 4;
  const int bh = b * 16 + h;
  const unsigned short* qp = qg + ((size_t)bh * 512 + qt * 32) * 64;
  const unsigned short* kp = kg + (size_t)bh * 512 * 64;
  const unsigned short* vp = vt + (size_t)bh * 64 * 512;

  const unsigned char* mrb = mbits + ((size_t)(b * 512 + qt * 32)) * 64;
  const unsigned char* wrb = wbits + ((size_t)(b * 512 + qt * 32)) * 64;
  unsigned int mby[2][4], wby[2][4];
  #pragma unroll
  for (int g = 0; g < 2; g++)
    #pragma unroll
    for (int rr = 0; rr < 4; rr++){
      mby[g][rr] = mrb[(g * 16 + w * 4 + rr) * 64 + l];
      wby[g][rr] = wrb[(g * 16 + w * 4 + rr) * 64 + l];
    }

  // ---- Phase A: QK^T on 128-col k-slice for 2 q-subtiles (indep chains) ----
  short8 qa[2][2];
  #pragma unroll
  for (int t = 0; t < 2; t++){
    qa[t][0] = *(const short8*)(qp + (t * 16 + lr) * 64 + lq * 8);
    qa[t][1] = *(const short8*)(qp + (t * 16 + lr) * 64 + 32 + lq * 8);
  }
  const float CEXP = 0.18033688011112042f;   // 0.125 * log2(e)
  #pragma unroll
  for (int kf = 0; kf < 8; kf++){
    const unsigned short* kr = kp + (size_t)(w * 128 + kf * 16 + lr) * 64;
    short8 k0 = *(const short8*)(kr + lq * 8);
    short8 k1 = *(const short8*)(kr + 32 + lq * 8);
    f32x4 a0 = {}, a1 = {};
    a0 = MFMA_BF16(qa[0][0], k0, a0);
    a1 = MFMA_BF16(qa[1][0], k0, a1);
    a0 = MFMA_BF16(qa[0][1], k1, a0);
    a1 = MFMA_BF16(qa[1][1], k1, a1);
    const int col = w * 128 + kf * 16 + lr;
    #pragma unroll
    for (int t = 0; t < 2; t++){
      f32x4 a = t ? a1 : a0;
      float e0 = __builtin_amdgcn_exp2f(a[0] * CEXP);
      float e1 = __builtin_amdgcn_exp2f(a[1] * CEXP);
      float e2 = __builtin_amdgcn_exp2f(a[2] * CEXP);
      float e3 = __builtin_amdgcn_exp2f(a[3] * CEXP);
      unsigned int p01 = cvtpk(e0, e1), p23 = cvtpk(e2, e3);
      const int row = t * 16 + lq * 4;
      sE[(row    ) * 520 + col] = (unsigned short)(p01 & 0xFFFFu);
      sE[(row + 1) * 520 + col] = (unsigned short)(p01 >> 16);
      sE[(row + 2) * 520 + col] = (unsigned short)(p23 & 0xFFFFu);
      sE[(row + 3) * 520 + col] = (unsigned short)(p23 >> 16);
    }
  }
  __syncthreads();

  // ---- Phase B: double masked softmax, 2 groups x 4 interleaved rows ----
  #pragma unroll
  for (int g = 0; g < 2; g++){
    const int row0 = g * 16 + w * 4;
    uint4 ev[4];
    #pragma unroll
    for (int rr = 0; rr < 4; rr++)
      ev[rr] = *(const uint4*)(sE + (row0 + rr) * 520 + l * 8);

    float em[4][8]; float z1[4];
    #pragma unroll
    for (int rr = 0; rr < 4; rr++){
      float e1[8];
      unpack8(ev[rr], e1);
      const unsigned int mb = mby[g][rr];
      float z = 0.f;
      #pragma unroll
      for (int j = 0; j < 8; j++){
        em[rr][j] = ((mb >> j) & 1u) ? e1[j] : 0.f;
        z += em[rr][j];
      }
      z1[rr] = z;
    }
    #pragma unroll
    for (int m = 32; m; m >>= 1){
      #pragma unroll
      for (int rr = 0; rr < 4; rr++) z1[rr] += __shfl_xor(z1[rr], m, 64);
    }
    float e2[4][8]; float z2[4];
    #pragma unroll
    for (int rr = 0; rr < 4; rr++){
      const float i1L = 1.4426950408889634f / z1[rr];
      const unsigned int wv = wby[g][rr];
      float z = 0.f;
      #pragma unroll
      for (int j = 0; j < 8; j++){
        float t = __builtin_amdgcn_exp2f(em[rr][j] * i1L);
        e2[rr][j] = ((wv >> j) & 1u) ? t : 0.f;
        z += e2[rr][j];
      }
      z2[rr] = z;
    }
    #pragma unroll
    for (int m = 32; m; m >>= 1){
      #pragma unroll
      for (int rr = 0; rr < 4; rr++) z2[rr] += __shfl_xor(z2[rr], m, 64);
    }
    #pragma unroll
    for (int rr = 0; rr < 4; rr++){
      uint4 oo;
      oo.x = cvtpk(e2[rr][0], e2[rr][1]); oo.y = cvtpk(e2[rr][2], e2[rr][3]);
      oo.z = cvtpk(e2[rr][4], e2[rr][5]); oo.w = cvtpk(e2[rr][6], e2[rr][7]);
      *(uint4*)(sE + (row0 + rr) * 520 + l * 8) = oo;
      if (l == 0) sfin[row0 + rr] = 1.f / (z2[rr] + 1e-10f);
    }
  }
  __syncthreads();

  // ---- Phase C: 2 po chains sharing each V frag; d-frag [16w,16w+16) ----
  {
    f32x4 po0 = {}, po1 = {};
    #pragma unroll
    for (int ks = 0; ks < 16; ks++){
      short8 vf = *(const short8*)(vp + (size_t)(w * 16 + lr) * 512 + ks * 32 + lq * 8);
      short8 af0 = *(const short8*)(sE + (     lr) * 520 + ks * 32 + lq * 8);
      short8 af1 = *(const short8*)(sE + (16 + lr) * 520 + ks * 32 + lq * 8);
      po0 = MFMA_BF16(af0, vf, po0);
      po1 = MFMA_BF16(af1, vf, po1);
    }
    #pragma unroll
    for (int rg = 0; rg < 4; rg++){
      const int r0 = lq * 4 + rg;
      outp[((size_t)(qt * 32 + r0) * 16 + b) * 1024 + h * 64 + w * 16 + lr]
          = f2bf(po0[rg] * sfin[r0]);
      outp[((size_t)(qt * 32 + 16 + r0) * 16 + b) * 1024 + h * 64 + w * 16 + lr]
          = f2bf(po1[rg] * sfin[16 + r0]);
    }
  }
}

// ---------------- gate + mix ----------------
__global__ __launch_bounds__(256) void gate_kernel(
    const unsigned short* __restrict__ outp, const unsigned short* __restrict__ rbb,
    const float* __restrict__ wba, const float* __restrict__ wbb,
    float* __restrict__ y)
{
  const int t = blockIdx.x * 4 + (threadIdx.x >> 6);
  const int l = threadIdx.x & 63;
  const unsigned short* o = outp + (size_t)t * 1024;
  const unsigned short* r = rbb + (size_t)t * 1024;
  float ov[16], rv[16];
  float acc = 0.f;
  #pragma unroll
  for (int j = 0; j < 16; j++){
    const int e = j * 64 + l;
    ov[j] = __uint_as_float((unsigned int)o[e] << 16);
    rv[j] = __uint_as_float((unsigned int)r[e] << 16);
    acc += ov[j] * wba[e] + rv[j] * wbb[e];
  }
  const float dot = wred_sum(acc);
  const float g = 1.f / (1.f + __builtin_amdgcn_exp2f(-dot * 1.4426950408889634f));
  float* yo = y + (size_t)t * 1024;
  #pragma unroll
  for (int j = 0; j < 16; j++){
    const int e = j * 64 + l;
    yo[e] = g * rv[j] + (1.f - g) * ov[j];
  }
}

// ---------------- launch ----------------
extern "C" void kernel_launch(void* const* d_in, const int* in_sizes, int n_in,
                              void* d_out, int out_size, void* d_ws, size_t ws_size,
                              hipStream_t stream)
{
  (void)in_sizes; (void)n_in; (void)out_size; (void)ws_size;
  const float* x   = (const float*)d_in[0];
  const int* mask  = (const int*)d_in[1];
  const int* wmask = (const int*)d_in[2];
  const float* Wq  = (const float*)d_in[3];
  const float* Wk  = (const float*)d_in[4];
  const float* Wv  = (const float*)d_in[5];
  const float* Ws  = (const float*)d_in[6];
  const float* Wb  = (const float*)d_in[7];

  char* ws = (char*)d_ws;
  unsigned short* xbf = (unsigned short*)ws; ws += 16777216;
  unsigned short* bm  = (unsigned short*)ws; ws += 8388608;
  unsigned short* qb  = (unsigned short*)ws; ws += 16777216;
  unsigned short* kb  = (unsigned short*)ws; ws += 16777216;
  unsigned short* vT  = (unsigned short*)ws; ws += 16777216;
  unsigned short* rbb = (unsigned short*)ws; ws += 16777216;
  unsigned short* op  = (unsigned short*)ws; ws += 16777216;
  float* wba = (float*)ws; ws += 4096;
  float* wbb = (float*)ws; ws += 4096;
  unsigned long long* mb64 = (unsigned long long*)xbf;
  unsigned long long* wb64 = (unsigned long long*)bm;

  cvt_x_kernel<<<8192, 256, 0, stream>>>(x, xbf);
  cvt_w_kernel<<<4096, 256, 0, stream>>>(Wq, Wk, Wv, Ws, bm);
  wb_prep_kernel<<<4, 256, 0, stream>>>(Wb, wba, wbb);
  gemm_proj_kernel<<<1024, 512, 0, stream>>>(xbf, bm, qb, kb, vT, rbb);
  mask_prep_kernel<<<16384, 256, 0, stream>>>(mask, wmask, mb64, wb64);
  attn_kernel<<<4096, 256, 0, stream>>>(qb, kb, vT,
      (const unsigned char*)mb64, (const unsigned char*)wb64, op);
  gate_kernel<<<2048, 256, 0, stream>>>(op, rbb, wba, wbb, (float*)d_out);
}